// Round 14
// baseline (215.402 us; speedup 1.0000x reference)
//
#include <hip/hip_runtime.h>
#include <hip/hip_bf16.h>
#include <hip/hip_fp16.h>

// GCN 2-layer: out = Ahat * relu(Ahat*(X W1)+b1) * W2 + b2
// Round 14 (on top of R13's multi-row gather waves):
//  - degree-sorted row permutation (counting sort, 64 bins, descending):
//    aggregate waves process equal-degree rows -> no exec-mask waste from
//    divergent loop trip counts (was E[max of 4 Poisson(16)] vs mean).
//  - replicated LDS histograms in passA_hist (x4) and bucket_csr (x2) to cut
//    LDS-atomic same-address serialization.
//  - everything else unchanged from R13.

#define N_FEAT_IN 64
#define B2SHIFT 9        // 512 dst nodes per coarse bucket
#define CHUNK 4096       // edges per block in pass A/B
#define DCHUNK 1024      // rows per block in degree sort

struct alignas(8) half4 { __half2 lo, hi; };

// ---- pass A: per-chunk bucket histogram (4-way replicated LDS) ----
__global__ __launch_bounds__(1024) void passA_hist(const int* __restrict__ dst,
                                                   int* __restrict__ H, int E) {
    __shared__ int h[4][256];
    int t = threadIdx.x;
    ((int*)h)[t] = 0;
    __syncthreads();
    int sub = (t >> 6) & 3;
    int base = blockIdx.x * CHUNK;
    int end = min(base + CHUNK, E);
    for (int i = base + t; i < end; i += 1024)
        atomicAdd(&h[sub][dst[i] >> B2SHIFT], 1);
    __syncthreads();
    if (t < 256) H[blockIdx.x * 256 + t] = h[0][t] + h[1][t] + h[2][t] + h[3][t];
}

// ---- col_scan_a: one block per column; exclusive scan over NR rows ----
__global__ __launch_bounds__(512) void col_scan_a(int* __restrict__ H,
                                                  int* __restrict__ ctot, int NR) {
    __shared__ int s[512];
    int b = blockIdx.x;
    int t = threadIdx.x;
    int v = (t < NR) ? H[t * 256 + b] : 0;
    s[t] = v;
    __syncthreads();
    for (int off = 1; off < 512; off <<= 1) {
        int a = (t >= off) ? s[t - off] : 0;
        __syncthreads();
        s[t] += a;
        __syncthreads();
    }
    if (t < NR) H[t * 256 + b] = s[t] - v;
    if (t == 511) ctot[b] = s[511];
}

// ---- col_scan_b: scan column totals -> per-bucket bases; row_ptr[n]=E ----
__global__ __launch_bounds__(256) void col_scan_b(const int* __restrict__ ctot,
                                                  int* __restrict__ cbase,
                                                  int* __restrict__ bbase,
                                                  int* __restrict__ row_ptr,
                                                  int NB, int n, int E) {
    __shared__ int s[256];
    int t = threadIdx.x;
    int v = ctot[t];
    s[t] = v;
    __syncthreads();
    for (int off = 1; off < 256; off <<= 1) {
        int a = (t >= off) ? s[t - off] : 0;
        __syncthreads();
        s[t] += a;
        __syncthreads();
    }
    int e = s[t] - v;
    cbase[t] = e;
    if (t < NB) bbase[t] = e;
    if (t == 0) { bbase[NB] = E; row_ptr[n] = E; }
}

// ---- pass B: place packed edges into private per-chunk runs ----
__global__ __launch_bounds__(1024) void passB_place(const int* __restrict__ src,
                                                    const int* __restrict__ dst,
                                                    const int* __restrict__ H,
                                                    const int* __restrict__ cbase,
                                                    unsigned* __restrict__ bedges, int E) {
    __shared__ int cur[256];
    int t = threadIdx.x;
    if (t < 256) cur[t] = H[blockIdx.x * 256 + t] + cbase[t];
    __syncthreads();
    int base = blockIdx.x * CHUNK;
    int end = min(base + CHUNK, E);
    for (int i = base + t; i < end; i += 1024) {
        int d = dst[i];
        int p = atomicAdd(&cur[d >> B2SHIFT], 1);  // LDS atomic
        bedges[p] = ((unsigned)src[i] << B2SHIFT) | (unsigned)(d & 511);
    }
}

// ---- merged: per-bucket hist (2x replicated) -> scan -> row_ptr/dinv -> CSR ----
__global__ __launch_bounds__(1024) void bucket_csr(const int* __restrict__ bbase,
                                                   const unsigned* __restrict__ bedges,
                                                   int* __restrict__ row_ptr,
                                                   float* __restrict__ dinv,
                                                   int* __restrict__ csr_src, int n) {
    __shared__ int lh[2][512];
    __shared__ int cur[512];
    int t = threadIdx.x;
    if (t < 512) { lh[0][t] = 0; lh[1][t] = 0; }
    __syncthreads();
    int sub = (t >> 6) & 1;
    int b = blockIdx.x;
    int beg = bbase[b], end = bbase[b + 1];
    for (int i = beg + t; i < end; i += 1024)
        atomicAdd(&lh[sub][bedges[i] & 511], 1);
    __syncthreads();
    if (t < 512) lh[0][t] += lh[1][t];
    __syncthreads();
    int c = (t < 512) ? lh[0][t] : 0;
    for (int off = 1; off < 512; off <<= 1) {
        int a = (t < 512 && t >= off) ? lh[0][t - off] : 0;
        __syncthreads();
        if (t < 512) lh[0][t] += a;
        __syncthreads();
    }
    if (t < 512) {
        int d = (b << B2SHIFT) + t;
        int excl = beg + lh[0][t] - c;
        cur[t] = excl;
        if (d < n) {
            row_ptr[d] = excl;
            dinv[d] = rsqrtf((float)c + 1.0f);
        }
    }
    __syncthreads();
    for (int i = beg + t; i < end; i += 1024) {
        unsigned v = bedges[i];
        int p = atomicAdd(&cur[v & 511], 1);  // LDS atomic
        csr_src[p] = (int)(v >> B2SHIFT);
    }
}

// ---- degree counting sort (descending): perm[0..n) = rows by deg desc ----
__global__ __launch_bounds__(256) void degA(const int* __restrict__ row_ptr,
                                            int* __restrict__ D, int n) {
    __shared__ int dh[64];
    int t = threadIdx.x;
    if (t < 64) dh[t] = 0;
    __syncthreads();
    int base = blockIdx.x * DCHUNK;
    int end = min(base + DCHUNK, n);
    for (int d = base + t; d < end; d += 256) {
        int key = 63 - min(row_ptr[d + 1] - row_ptr[d], 63);
        atomicAdd(&dh[key], 1);
    }
    __syncthreads();
    if (t < 64) D[blockIdx.x * 64 + t] = dh[t];
}

__global__ __launch_bounds__(128) void degScanA(int* __restrict__ D,
                                                int* __restrict__ dtot, int NR2) {
    __shared__ int s[128];
    int b = blockIdx.x;   // bin
    int t = threadIdx.x;  // chunk
    int v = (t < NR2) ? D[t * 64 + b] : 0;
    s[t] = v;
    __syncthreads();
    for (int off = 1; off < 128; off <<= 1) {
        int a = (t >= off) ? s[t - off] : 0;
        __syncthreads();
        s[t] += a;
        __syncthreads();
    }
    if (t < NR2) D[t * 64 + b] = s[t] - v;
    if (t == 127) dtot[b] = s[127];
}

__global__ __launch_bounds__(64) void degScanB(const int* __restrict__ dtot,
                                               int* __restrict__ dbase) {
    __shared__ int s[64];
    int t = threadIdx.x;
    int v = dtot[t];
    s[t] = v;
    __syncthreads();
    for (int off = 1; off < 64; off <<= 1) {
        int a = (t >= off) ? s[t - off] : 0;
        __syncthreads();
        s[t] += a;
        __syncthreads();
    }
    dbase[t] = s[t] - v;
}

__global__ __launch_bounds__(256) void degScatter(const int* __restrict__ row_ptr,
                                                  const int* __restrict__ D,
                                                  const int* __restrict__ dbase,
                                                  int* __restrict__ perm, int n) {
    __shared__ int cur[64];
    int t = threadIdx.x;
    if (t < 64) cur[t] = D[blockIdx.x * 64 + t] + dbase[t];
    __syncthreads();
    int base = blockIdx.x * DCHUNK;
    int end = min(base + DCHUNK, n);
    for (int d = base + t; d < end; d += 256) {
        int key = 63 - min(row_ptr[d + 1] - row_ptr[d], 63);
        int pos = atomicAdd(&cur[key], 1);
        perm[pos] = d;
    }
}

// ---- GEMM layer1: xs1[n+1,64] fp16 = half( dinv[row] * (X W1) ); pad row 0 ----
__global__ __launch_bounds__(256) void gemm64(const float* __restrict__ A,
                                              const float* __restrict__ W,
                                              const float* __restrict__ dinv,
                                              __half* __restrict__ outh, int n) {
    constexpr int K = 64, FO = 64, CPT = 16;
    __shared__ float As[64][K + 4];
    __shared__ float Ws[K][FO];

    const int t = threadIdx.x;
    const int r0 = blockIdx.x * 64;

    if (blockIdx.x == 0 && t < FO)
        outh[(size_t)n * FO + t] = __float2half(0.f);

    for (int i = t; i < K * FO / 4; i += 256) {
        int k = i / (FO / 4);
        int c4 = (i % (FO / 4)) * 4;
        *(float4*)&Ws[k][c4] = *(const float4*)&W[k * FO + c4];
    }
    for (int i = t; i < 1024; i += 256) {
        int row = i / 16;
        int c4 = (i % 16) * 4;
        int g = r0 + row;
        float4 v = make_float4(0.f, 0.f, 0.f, 0.f);
        if (g < n) v = *(const float4*)&A[(size_t)g * K + c4];
        *(float4*)&As[row][c4] = v;
    }
    __syncthreads();

    const int row = t >> 2;
    const int c0 = (t & 3) * CPT;
    float acc[CPT];
#pragma unroll
    for (int j = 0; j < CPT; ++j) acc[j] = 0.f;
#pragma unroll
    for (int k = 0; k < K; ++k) {
        float xv = As[row][k];
#pragma unroll
        for (int j = 0; j < CPT; ++j) acc[j] = fmaf(xv, Ws[k][c0 + j], acc[j]);
    }

    int g = r0 + row;
    if (g < n) {
        float sc = dinv[g];
#pragma unroll
        for (int j4 = 0; j4 < CPT; j4 += 4) {
            half4 h;
            h.lo = __floats2half2_rn(acc[j4] * sc, acc[j4 + 1] * sc);
            h.hi = __floats2half2_rn(acc[j4 + 2] * sc, acc[j4 + 3] * sc);
            *(half4*)&outh[(size_t)g * FO + c0 + j4] = h;
        }
    }
}

// ---- agg64: 4 rows/wave (degree-sorted), 16 lanes/row, half4/lane ----
__global__ __launch_bounds__(256) void agg64(const int* __restrict__ perm,
                                             const int* __restrict__ row_ptr,
                                             const int* __restrict__ csr_src,
                                             const float* __restrict__ dinv,
                                             const __half* __restrict__ xs1,
                                             const float* __restrict__ b1,
                                             __half* __restrict__ th, int n) {
    int slot = blockIdx.x * 16 + (threadIdx.x >> 4);
    if (slot >= n) return;
    int d = perm[slot];
    int c = threadIdx.x & 15;

    int beg = row_ptr[d];
    int end = row_ptr[d + 1];

    half4 sv = *(const half4*)&xs1[(size_t)d * 64 + 4 * c];  // self-loop
    float2 slo = __half22float2(sv.lo), shi = __half22float2(sv.hi);
    float a0 = slo.x, a1 = slo.y, a2 = shi.x, a3 = shi.y;

    for (int jb = beg; jb < end; jb += 8) {
        int idx[8];
#pragma unroll
        for (int k = 0; k < 8; ++k) {
            int j = jb + k;
            int s = csr_src[min(j, end - 1)];
            idx[k] = (j < end) ? s : n;   // n = zero pad row
        }
        half4 v[8];
#pragma unroll
        for (int k = 0; k < 8; ++k)
            v[k] = *(const half4*)&xs1[(size_t)idx[k] * 64 + 4 * c];
#pragma unroll
        for (int k = 0; k < 8; ++k) {
            float2 lo = __half22float2(v[k].lo), hi = __half22float2(v[k].hi);
            a0 += lo.x; a1 += lo.y; a2 += hi.x; a3 += hi.y;
        }
    }

    float di = dinv[d];
    float4 bv = *(const float4*)&b1[4 * c];
    float t0 = fmaxf(fmaf(di, a0, bv.x), 0.f);
    float t1 = fmaxf(fmaf(di, a1, bv.y), 0.f);
    float t2 = fmaxf(fmaf(di, a2, bv.z), 0.f);
    float t3 = fmaxf(fmaf(di, a3, bv.w), 0.f);
    half4 h;
    h.lo = __floats2half2_rn(t0, t1);
    h.hi = __floats2half2_rn(t2, t3);
    *(half4*)&th[(size_t)d * 64 + 4 * c] = h;  // one 128B line per row
}

// ---- gemm32h: xs2[n+1,32] fp16 = half( dinv[row] * (t[n,64] W2) ); pad row ----
__global__ __launch_bounds__(256) void gemm32h(const __half* __restrict__ Ah,
                                               const float* __restrict__ W,
                                               const float* __restrict__ dinv,
                                               __half* __restrict__ outh, int n) {
    constexpr int K = 64, FO = 32, CPT = 8;
    __shared__ float As[64][K + 4];
    __shared__ float Ws[K][FO];

    const int t = threadIdx.x;
    const int r0 = blockIdx.x * 64;

    if (blockIdx.x == 0 && t < FO)
        outh[(size_t)n * FO + t] = __float2half(0.f);

    for (int i = t; i < K * FO / 4; i += 256) {
        int k = i / (FO / 4);
        int c4 = (i % (FO / 4)) * 4;
        *(float4*)&Ws[k][c4] = *(const float4*)&W[k * FO + c4];
    }
    for (int i = t; i < 1024; i += 256) {
        int row = i / 16;
        int c4 = (i % 16) * 4;
        int g = r0 + row;
        float4 v = make_float4(0.f, 0.f, 0.f, 0.f);
        if (g < n) {
            half4 hv = *(const half4*)&Ah[(size_t)g * K + c4];
            float2 lo = __half22float2(hv.lo), hi = __half22float2(hv.hi);
            v = make_float4(lo.x, lo.y, hi.x, hi.y);
        }
        *(float4*)&As[row][c4] = v;
    }
    __syncthreads();

    const int row = t >> 2;
    const int c0 = (t & 3) * CPT;
    float acc[CPT];
#pragma unroll
    for (int j = 0; j < CPT; ++j) acc[j] = 0.f;
#pragma unroll
    for (int k = 0; k < K; ++k) {
        float xv = As[row][k];
#pragma unroll
        for (int j = 0; j < CPT; ++j) acc[j] = fmaf(xv, Ws[k][c0 + j], acc[j]);
    }

    int g = r0 + row;
    if (g < n) {
        float sc = dinv[g];
#pragma unroll
        for (int j4 = 0; j4 < CPT; j4 += 4) {
            half4 h;
            h.lo = __floats2half2_rn(acc[j4] * sc, acc[j4 + 1] * sc);
            h.hi = __floats2half2_rn(acc[j4 + 2] * sc, acc[j4 + 3] * sc);
            *(half4*)&outh[(size_t)g * FO + c0 + j4] = h;
        }
    }
}

// ---- agg32: 8 rows/wave (degree-sorted), 8 lanes/row, half4/lane ----
__global__ __launch_bounds__(256) void agg32(const int* __restrict__ perm,
                                             const int* __restrict__ row_ptr,
                                             const int* __restrict__ csr_src,
                                             const float* __restrict__ dinv,
                                             const __half* __restrict__ xs2,
                                             const float* __restrict__ b2,
                                             float* __restrict__ out, int n) {
    int slot = blockIdx.x * 32 + (threadIdx.x >> 3);
    if (slot >= n) return;
    int d = perm[slot];
    int c = threadIdx.x & 7;

    int beg = row_ptr[d];
    int end = row_ptr[d + 1];

    half4 sv = *(const half4*)&xs2[(size_t)d * 32 + 4 * c];  // self-loop
    float2 slo = __half22float2(sv.lo), shi = __half22float2(sv.hi);
    float a0 = slo.x, a1 = slo.y, a2 = shi.x, a3 = shi.y;

    for (int jb = beg; jb < end; jb += 8) {
        int idx[8];
#pragma unroll
        for (int k = 0; k < 8; ++k) {
            int j = jb + k;
            int s = csr_src[min(j, end - 1)];
            idx[k] = (j < end) ? s : n;
        }
        half4 v[8];
#pragma unroll
        for (int k = 0; k < 8; ++k)
            v[k] = *(const half4*)&xs2[(size_t)idx[k] * 32 + 4 * c];
#pragma unroll
        for (int k = 0; k < 8; ++k) {
            float2 lo = __half22float2(v[k].lo), hi = __half22float2(v[k].hi);
            a0 += lo.x; a1 += lo.y; a2 += hi.x; a3 += hi.y;
        }
    }

    float di = dinv[d];
    float4 bv = *(const float4*)&b2[4 * c];
    float4 r;
    r.x = fmaf(di, a0, bv.x);
    r.y = fmaf(di, a1, bv.y);
    r.z = fmaf(di, a2, bv.z);
    r.w = fmaf(di, a3, bv.w);
    *(float4*)&out[(size_t)d * 32 + 4 * c] = r;  // one 128B line per row
}

extern "C" void kernel_launch(void* const* d_in, const int* in_sizes, int n_in,
                              void* d_out, int out_size, void* d_ws, size_t ws_size,
                              hipStream_t stream) {
    const float* x  = (const float*)d_in[0];   // [n, 64]
    const int*   ei = (const int*)d_in[1];     // [2, E]
    const float* W1 = (const float*)d_in[2];   // [64, 64]
    const float* b1 = (const float*)d_in[3];   // [64]
    const float* W2 = (const float*)d_in[4];   // [64, 32]
    const float* b2 = (const float*)d_in[5];   // [32]
    float* out = (float*)d_out;                // [n, 32]

    const int n = in_sizes[0] / N_FEAT_IN;     // 100000
    const int E = in_sizes[1] / 2;             // 1600000
    const int* srcI = ei;
    const int* dstI = ei + E;

    const int NB  = (n + 511) >> B2SHIFT;      // 196 coarse buckets
    const int NR  = (E + CHUNK - 1) / CHUNK;   // 391 chunks
    const int NR2 = (n + DCHUNK - 1) / DCHUNK; // 98 degree-sort chunks

    // workspace layout (256B aligned)
    char* ws = (char*)d_ws;
    size_t off = 0;
    auto alloc = [&](size_t bytes) {
        void* p = ws + off;
        off += (bytes + 255) & ~(size_t)255;
        return p;
    };
    float*    dinv    = (float*)alloc((size_t)n * 4);
    int*      row_ptr = (int*)alloc((size_t)(n + 1) * 4);
    int*      bbase   = (int*)alloc((size_t)(NB + 1) * 4);
    int*      ctot    = (int*)alloc((size_t)256 * 4);
    int*      cbase   = (int*)alloc((size_t)256 * 4);
    int*      H       = (int*)alloc((size_t)NR * 256 * 4);        // ~400KB
    unsigned* bedges  = (unsigned*)alloc((size_t)E * 4);
    int*      csr_src = (int*)alloc((size_t)E * 4);
    int*      D       = (int*)alloc((size_t)NR2 * 64 * 4);
    int*      dtot    = (int*)alloc((size_t)64 * 4);
    int*      dbase   = (int*)alloc((size_t)64 * 4);
    int*      perm    = (int*)alloc((size_t)n * 4);
    __half*   xs1     = (__half*)alloc((size_t)(n + 1) * 64 * 2); // +pad row
    __half*   th      = (__half*)alloc((size_t)n * 64 * 2);
    __half*   xs2     = (__half*)alloc((size_t)(n + 1) * 32 * 2); // +pad row

    // 1) atomic-free bucket sort by dst>>9
    passA_hist<<<NR, 1024, 0, stream>>>(dstI, H, E);
    col_scan_a<<<256, 512, 0, stream>>>(H, ctot, NR);
    col_scan_b<<<1, 256, 0, stream>>>(ctot, cbase, bbase, row_ptr, NB, n, E);
    passB_place<<<NR, 1024, 0, stream>>>(srcI, dstI, H, cbase, bedges, E);

    // 2) merged: row_ptr + dinv + CSR scatter
    bucket_csr<<<NB, 1024, 0, stream>>>(bbase, bedges, row_ptr, dinv, csr_src, n);

    // 3) degree-descending permutation (wave load balance for aggregates)
    degA<<<NR2, 256, 0, stream>>>(row_ptr, D, n);
    degScanA<<<64, 128, 0, stream>>>(D, dtot, NR2);
    degScanB<<<1, 64, 0, stream>>>(dtot, dbase);
    degScatter<<<NR2, 256, 0, stream>>>(row_ptr, D, dbase, perm, n);

    // 4) layer 1 GEMM: xs1 = half(dinv .* (X W1))
    gemm64<<<(n + 63) / 64, 256, 0, stream>>>(x, W1, dinv, xs1, n);

    // 5) layer-1 aggregate: t = relu(dinv*(gather+self) + b1)
    agg64<<<(n + 15) / 16, 256, 0, stream>>>(perm, row_ptr, csr_src, dinv, xs1, b1, th, n);

    // 6) layer-2 transform: xs2 = half(dinv .* (t W2))
    gemm32h<<<(n + 63) / 64, 256, 0, stream>>>(th, W2, dinv, xs2, n);

    // 7) layer-2 aggregate -> out
    agg32<<<(n + 31) / 32, 256, 0, stream>>>(perm, row_ptr, csr_src, dinv, xs2, b2, out, n);
}